// Round 1
// baseline (447.971 us; speedup 1.0000x reference)
//
#include <hip/hip_runtime.h>
#include <hip/hip_bf16.h>

// ContrastiveLoss: N=16384, D=128.
// loss = mean_i log1p(rep_i / (att_i + EPS)), rep_i = mean_j exp(-max(sq1_i+sq2_j-2*x_i.y_j,0))
// att_i = exp(-||x_i - y_i||^2);  TAU=0.5 => 2*TAU = 1.
// Outputs: [loss, mean(att), mean(rep)]  (3 fp32 scalars)

#define EPS 1e-8f
#define D_DIM 128

typedef __attribute__((ext_vector_type(8))) short bf16x8;
typedef __attribute__((ext_vector_type(4))) float f32x4;

static __device__ inline ushort f2bf(float x) {
    __hip_bfloat16 h = __float2bfloat16(x);
    union { __hip_bfloat16 h; ushort u; } cvt;
    cvt.h = h;
    return cvt.u;
}

// One wave per row: row norms, attraction, bf16 casts, zero rep.
__global__ __launch_bounds__(64) void prep_kernel(
    const float* __restrict__ X1, const float* __restrict__ X2,
    ushort* __restrict__ B1, ushort* __restrict__ B2,
    float* __restrict__ sq1, float* __restrict__ sq2,
    float* __restrict__ att, float* __restrict__ rep)
{
    const int i = blockIdx.x;
    const int l = threadIdx.x;            // 0..63, 2 floats each -> 128
    const float2 a = ((const float2*)(X1 + (size_t)i * D_DIM))[l];
    const float2 b = ((const float2*)(X2 + (size_t)i * D_DIM))[l];

    ushort2 pa; pa.x = f2bf(a.x); pa.y = f2bf(a.y);
    ushort2 pb; pb.x = f2bf(b.x); pb.y = f2bf(b.y);
    ((ushort2*)(B1 + (size_t)i * D_DIM))[l] = pa;
    ((ushort2*)(B2 + (size_t)i * D_DIM))[l] = pb;

    float s1 = a.x * a.x + a.y * a.y;
    float s2 = b.x * b.x + b.y * b.y;
    float dx = a.x - b.x, dy = a.y - b.y;
    float ps = dx * dx + dy * dy;
    #pragma unroll
    for (int m = 32; m; m >>= 1) {
        s1 += __shfl_xor(s1, m, 64);
        s2 += __shfl_xor(s2, m, 64);
        ps += __shfl_xor(ps, m, 64);
    }
    if (l == 0) {
        sq1[i] = s1;
        sq2[i] = s2;
        att[i] = __expf(-ps);
        rep[i] = 0.f;
    }
}

// Fused cross-GEMM + exp + row-sum. Tile 128x128 per block, 4 waves of 64x64.
// NT GEMM: cross[i][j] = sum_d A[i,d]*B[j,d]; both operands row-major [N][128],
// fragments loaded directly from global (L2/L3-resident, 4 MB each).
__global__ __launch_bounds__(256) void cross_kernel(
    const ushort* __restrict__ B1, const ushort* __restrict__ B2,
    const float* __restrict__ sq1, const float* __restrict__ sq2,
    float* __restrict__ rep)
{
    const int lane = threadIdx.x & 63;
    const int wid  = threadIdx.x >> 6;     // 0..3
    const int wy = wid >> 1, wx = wid & 1; // 2x2 wave grid
    const int row_base = blockIdx.y * 128 + wy * 64;
    const int col_base = blockIdx.x * 128 + wx * 64;
    const int lr = lane & 15;              // fragment row within 16
    const int lk = (lane >> 4) * 8;        // k-slice start (8 bf16)

    f32x4 acc[4][4];
    #pragma unroll
    for (int m = 0; m < 4; ++m)
        #pragma unroll
        for (int n = 0; n < 4; ++n)
            acc[m][n] = (f32x4){0.f, 0.f, 0.f, 0.f};

    const ushort* Arow = B1 + (size_t)(row_base + lr) * D_DIM + lk;
    const ushort* Brow = B2 + (size_t)(col_base + lr) * D_DIM + lk;

    #pragma unroll
    for (int kc = 0; kc < 4; ++kc) {       // K = 128 = 4 x 32
        bf16x8 aF[4], bF[4];
        #pragma unroll
        for (int m = 0; m < 4; ++m)
            aF[m] = *(const bf16x8*)(Arow + m * 16 * D_DIM + kc * 32);
        #pragma unroll
        for (int n = 0; n < 4; ++n)
            bF[n] = *(const bf16x8*)(Brow + n * 16 * D_DIM + kc * 32);
        #pragma unroll
        for (int m = 0; m < 4; ++m)
            #pragma unroll
            for (int n = 0; n < 4; ++n)
                acc[m][n] = __builtin_amdgcn_mfma_f32_16x16x32_bf16(
                    aF[m], bF[n], acc[m][n], 0, 0, 0);
    }

    // Epilogue: e = exp(min(2c - sq1 - sq2, 0)); row-sum over this block's 64 cols.
    // C/D layout (16x16x32): col = lane&15, row = (lane>>4)*4 + reg.
    const int cg = lane >> 4;
    #pragma unroll
    for (int m = 0; m < 4; ++m) {
        #pragma unroll
        for (int r = 0; r < 4; ++r) {
            const int row = row_base + m * 16 + cg * 4 + r;
            const float s1v = sq1[row];
            float partial = 0.f;
            #pragma unroll
            for (int n = 0; n < 4; ++n) {
                const int col = col_base + n * 16 + lr;
                const float t = 2.0f * acc[m][n][r] - s1v - sq2[col];
                partial += __expf(fminf(t, 0.0f));
            }
            // reduce across the 16 lanes (col dimension) of this cg group
            partial += __shfl_xor(partial, 1, 64);
            partial += __shfl_xor(partial, 2, 64);
            partial += __shfl_xor(partial, 4, 64);
            partial += __shfl_xor(partial, 8, 64);
            if (lr == 0) atomicAdd(&rep[row], partial);
        }
    }
}

// Final: loss = mean log1p((rep_i/N)/(att_i+EPS)), mean att, mean rep/N.
__global__ __launch_bounds__(256) void final_kernel(
    const float* __restrict__ rep, const float* __restrict__ att,
    float* __restrict__ out, int N)
{
    __shared__ float sm[3][4];
    const float inv = 1.0f / (float)N;
    float ls = 0.f, sa = 0.f, sr = 0.f;
    for (int i = threadIdx.x; i < N; i += 256) {
        const float rp = rep[i] * inv;
        const float at = att[i];
        ls += log1pf(rp / (at + EPS));
        sa += at;
        sr += rp;
    }
    #pragma unroll
    for (int m = 32; m; m >>= 1) {
        ls += __shfl_xor(ls, m, 64);
        sa += __shfl_xor(sa, m, 64);
        sr += __shfl_xor(sr, m, 64);
    }
    const int wid = threadIdx.x >> 6, lane = threadIdx.x & 63;
    if (lane == 0) { sm[0][wid] = ls; sm[1][wid] = sa; sm[2][wid] = sr; }
    __syncthreads();
    if (threadIdx.x == 0) {
        float L = 0.f, A = 0.f, R = 0.f;
        #pragma unroll
        for (int w = 0; w < 4; ++w) { L += sm[0][w]; A += sm[1][w]; R += sm[2][w]; }
        out[0] = L * inv;
        out[1] = A * inv;
        out[2] = R * inv;
    }
}

extern "C" void kernel_launch(void* const* d_in, const int* in_sizes, int n_in,
                              void* d_out, int out_size, void* d_ws, size_t ws_size,
                              hipStream_t stream)
{
    const float* X1 = (const float*)d_in[0];
    const float* X2 = (const float*)d_in[1];
    const int N = in_sizes[0] / D_DIM;   // 16384
    float* out = (float*)d_out;

    char* ws = (char*)d_ws;
    ushort* B1 = (ushort*)ws;                                  // N*128*2 B
    ushort* B2 = (ushort*)(ws + (size_t)N * D_DIM * 2);        // N*128*2 B
    float* sq1 = (float*)(ws + (size_t)N * D_DIM * 4);
    float* sq2 = sq1 + N;
    float* att = sq2 + N;
    float* rep = att + N;
    // total ws use: N*512 + 16*N bytes ≈ 8.65 MB

    prep_kernel<<<N, 64, 0, stream>>>(X1, X2, B1, B2, sq1, sq2, att, rep);
    dim3 grid(N / 128, N / 128);
    cross_kernel<<<grid, 256, 0, stream>>>(B1, B2, sq1, sq2, rep);
    final_kernel<<<1, 256, 0, stream>>>(rep, att, out, N);
}

// Round 2
// 274.929 us; speedup vs baseline: 1.6294x; 1.6294x over previous
//
#include <hip/hip_runtime.h>
#include <hip/hip_bf16.h>

// ContrastiveLoss: N=16384, D=128.
// loss = mean_i log1p(rep_i / (att_i + EPS)), rep_i = mean_j exp(-max(sq1_i+sq2_j-2*x_i.y_j,0))
// att_i = exp(-||x_i - y_i||^2);  TAU=0.5 => 2*TAU = 1.
// Outputs: [loss, mean(att), mean(rep)]  (3 fp32 scalars)

#define EPS 1e-8f
#define D_DIM 128

typedef __attribute__((ext_vector_type(8))) short bf16x8;
typedef __attribute__((ext_vector_type(4))) float f32x4;

typedef __attribute__((address_space(1))) const unsigned int gu32_t;
typedef __attribute__((address_space(3))) unsigned int lu32_t;

static __device__ inline void gload_lds16(const void* g, void* l) {
    // 16-byte-per-lane global -> LDS direct copy (wave-uniform LDS base + lane*16)
    __builtin_amdgcn_global_load_lds((gu32_t*)g, (lu32_t*)l, 16, 0, 0);
}

static __device__ inline ushort f2bf(float x) {
    union { __hip_bfloat16 h; ushort u; } cvt;
    cvt.h = __float2bfloat16(x);
    return cvt.u;
}

// One wave per row: row norms, attraction, bf16 casts, zero rep.
__global__ __launch_bounds__(64) void prep_kernel(
    const float* __restrict__ X1, const float* __restrict__ X2,
    ushort* __restrict__ B1, ushort* __restrict__ B2,
    float* __restrict__ sq1, float* __restrict__ sq2,
    float* __restrict__ att, float* __restrict__ rep)
{
    const int i = blockIdx.x;
    const int l = threadIdx.x;            // 0..63, 2 floats each -> 128
    const float2 a = ((const float2*)(X1 + (size_t)i * D_DIM))[l];
    const float2 b = ((const float2*)(X2 + (size_t)i * D_DIM))[l];

    ushort2 pa; pa.x = f2bf(a.x); pa.y = f2bf(a.y);
    ushort2 pb; pb.x = f2bf(b.x); pb.y = f2bf(b.y);
    ((ushort2*)(B1 + (size_t)i * D_DIM))[l] = pa;
    ((ushort2*)(B2 + (size_t)i * D_DIM))[l] = pb;

    float s1 = a.x * a.x + a.y * a.y;
    float s2 = b.x * b.x + b.y * b.y;
    float dx = a.x - b.x, dy = a.y - b.y;
    float ps = dx * dx + dy * dy;
    #pragma unroll
    for (int m = 32; m; m >>= 1) {
        s1 += __shfl_xor(s1, m, 64);
        s2 += __shfl_xor(s2, m, 64);
        ps += __shfl_xor(ps, m, 64);
    }
    if (l == 0) {
        sq1[i] = s1;
        sq2[i] = s2;
        att[i] = __expf(-ps);
        rep[i] = 0.f;
    }
}

// Fused cross-GEMM + exp + row-sum. 128x128 tile/block, 4 waves in a 2x2 grid
// of 64x64 sub-tiles. K = D = 128 entirely in one LDS-staged tile: each tile
// (128 rows x 128 cols bf16) is CONTIGUOUS 32 KB in global, staged via
// global_load_lds width=16 with inverse-swizzled source; ds_read applies the
// same XOR swizzle (rule: linear dest + inv-swz source + swz read).
__global__ __launch_bounds__(256, 2) void cross_kernel(
    const ushort* __restrict__ B1, const ushort* __restrict__ B2,
    const float* __restrict__ sq1, const float* __restrict__ sq2,
    float* __restrict__ rep)
{
    __shared__ ushort ldsA[128 * 128];   // 32 KB
    __shared__ ushort ldsB[128 * 128];   // 32 KB
    __shared__ float  ldsRed[2][128];    // per-wx row partials

    const int t    = threadIdx.x;
    const int lane = t & 63;
    const int wid  = t >> 6;             // 0..3
    const int wy = wid >> 1, wx = wid & 1;
    const int lr = lane & 15;            // fragment row/col within 16
    const int kg = lane >> 4;            // k-group (0..3), also C/D row group

    const int brow = blockIdx.y * 128;
    const int bcol = blockIdx.x * 128;

    // ---- stage: 2 x 32 KB contiguous copies, 8 iters x 4 KB each ----
    const char* gA = (const char*)(B1 + (size_t)brow * D_DIM);
    const char* gB = (const char*)(B2 + (size_t)bcol * D_DIM);
    #pragma unroll
    for (int it = 0; it < 8; ++it) {
        const unsigned Lb = it * 4096u + wid * 1024u;     // wave-uniform LDS base
        const unsigned L  = Lb + lane * 16u;              // this lane's linear dest
        const unsigned src = L ^ (((L >> 8) & 7u) << 4);  // inverse-swizzled source
        gload_lds16(gA + src, (char*)ldsA + Lb);
        gload_lds16(gB + src, (char*)ldsB + Lb);
    }
    __syncthreads();

    // ---- MFMA: K=128 in 4 chunks of 32 ----
    f32x4 acc[4][4];
    #pragma unroll
    for (int m = 0; m < 4; ++m)
        #pragma unroll
        for (int n = 0; n < 4; ++n)
            acc[m][n] = (f32x4){0.f, 0.f, 0.f, 0.f};

    #pragma unroll
    for (int kc = 0; kc < 4; ++kc) {
        bf16x8 aF[4], bF[4];
        #pragma unroll
        for (int m = 0; m < 4; ++m) {
            const int row = wy * 64 + m * 16 + lr;
            const unsigned addr = (unsigned)(row * 256 + kc * 64 + kg * 16)
                                  ^ ((unsigned)(row & 7) << 4);
            aF[m] = *(const bf16x8*)((const char*)ldsA + addr);
        }
        #pragma unroll
        for (int n = 0; n < 4; ++n) {
            const int row = wx * 64 + n * 16 + lr;
            const unsigned addr = (unsigned)(row * 256 + kc * 64 + kg * 16)
                                  ^ ((unsigned)(row & 7) << 4);
            bF[n] = *(const bf16x8*)((const char*)ldsB + addr);
        }
        #pragma unroll
        for (int m = 0; m < 4; ++m)
            #pragma unroll
            for (int n = 0; n < 4; ++n)
                acc[m][n] = __builtin_amdgcn_mfma_f32_16x16x32_bf16(
                    aF[m], bF[n], acc[m][n], 0, 0, 0);
    }

    // ---- epilogue: exp + row-sum over this wave's 64 cols ----
    // C/D layout (16x16x32): col = lane&15 (=lr), row = (lane>>4)*4 + reg (=kg*4+r)
    #pragma unroll
    for (int m = 0; m < 4; ++m) {
        #pragma unroll
        for (int r = 0; r < 4; ++r) {
            const int rowl = wy * 64 + m * 16 + kg * 4 + r;
            const float s1v = sq1[brow + rowl];
            float partial = 0.f;
            #pragma unroll
            for (int n = 0; n < 4; ++n) {
                const int col = bcol + wx * 64 + n * 16 + lr;
                const float tt = 2.0f * acc[m][n][r] - s1v - sq2[col];
                partial += __expf(fminf(tt, 0.0f));
            }
            partial += __shfl_xor(partial, 1, 64);
            partial += __shfl_xor(partial, 2, 64);
            partial += __shfl_xor(partial, 4, 64);
            partial += __shfl_xor(partial, 8, 64);
            if (lr == 0) ldsRed[wx][rowl] = partial;   // each (wx,rowl) written once
        }
    }
    __syncthreads();
    if (t < 128) {
        atomicAdd(&rep[brow + t], ldsRed[0][t] + ldsRed[1][t]);
    }
}

// Final: loss = mean log1p((rep_i/N)/(att_i+EPS)), mean att, mean rep/N.
__global__ __launch_bounds__(256) void final_kernel(
    const float* __restrict__ rep, const float* __restrict__ att,
    float* __restrict__ out, int N)
{
    __shared__ float sm[3][4];
    const float inv = 1.0f / (float)N;
    float ls = 0.f, sa = 0.f, sr = 0.f;
    for (int i = threadIdx.x; i < N; i += 256) {
        const float rp = rep[i] * inv;
        const float at = att[i];
        ls += log1pf(rp / (at + EPS));
        sa += at;
        sr += rp;
    }
    #pragma unroll
    for (int m = 32; m; m >>= 1) {
        ls += __shfl_xor(ls, m, 64);
        sa += __shfl_xor(sa, m, 64);
        sr += __shfl_xor(sr, m, 64);
    }
    const int wid = threadIdx.x >> 6, lane = threadIdx.x & 63;
    if (lane == 0) { sm[0][wid] = ls; sm[1][wid] = sa; sm[2][wid] = sr; }
    __syncthreads();
    if (threadIdx.x == 0) {
        float L = 0.f, A = 0.f, R = 0.f;
        #pragma unroll
        for (int w = 0; w < 4; ++w) { L += sm[0][w]; A += sm[1][w]; R += sm[2][w]; }
        out[0] = L * inv;
        out[1] = A * inv;
        out[2] = R * inv;
    }
}

extern "C" void kernel_launch(void* const* d_in, const int* in_sizes, int n_in,
                              void* d_out, int out_size, void* d_ws, size_t ws_size,
                              hipStream_t stream)
{
    const float* X1 = (const float*)d_in[0];
    const float* X2 = (const float*)d_in[1];
    const int N = in_sizes[0] / D_DIM;   // 16384
    float* out = (float*)d_out;

    char* ws = (char*)d_ws;
    ushort* B1 = (ushort*)ws;                                  // N*128*2 B
    ushort* B2 = (ushort*)(ws + (size_t)N * D_DIM * 2);        // N*128*2 B
    float* sq1 = (float*)(ws + (size_t)N * D_DIM * 4);
    float* sq2 = sq1 + N;
    float* att = sq2 + N;
    float* rep = att + N;
    // total ws use: N*512 + 16*N bytes ~= 8.65 MB

    prep_kernel<<<N, 64, 0, stream>>>(X1, X2, B1, B2, sq1, sq2, att, rep);
    dim3 grid(N / 128, N / 128);
    cross_kernel<<<grid, 256, 0, stream>>>(B1, B2, sq1, sq2, rep);
    final_kernel<<<1, 256, 0, stream>>>(rep, att, out, N);
}

// Round 3
// 260.191 us; speedup vs baseline: 1.7217x; 1.0566x over previous
//
#include <hip/hip_runtime.h>
#include <hip/hip_bf16.h>

// ContrastiveLoss: N=16384, D=128.
// loss = mean_i log1p(rep_i / (att_i + EPS)), rep_i = mean_j exp(-(sq1_i+sq2_j-2*x_i.y_j))
// att_i = exp(-||x_i - y_i||^2);  TAU=0.5 => 2*TAU = 1.
// exp folded to native exp2: B2 pre-scaled by 2/ln2, sq1/sq2 by 1/ln2.
// Outputs: [loss, mean(att), mean(rep)]  (3 fp32 scalars)

#define EPS 1e-8f
#define D_DIM 128
#define INV_LN2 1.44269504088896f
#define SCALE_B 2.88539008177793f   // 2/ln2

typedef __attribute__((ext_vector_type(8))) short bf16x8;
typedef __attribute__((ext_vector_type(4))) float f32x4;

typedef __attribute__((address_space(1))) const unsigned int gu32_t;
typedef __attribute__((address_space(3))) unsigned int lu32_t;

static __device__ inline void gload_lds16(const void* g, void* l) {
    // 16-byte-per-lane global -> LDS direct copy (wave-uniform LDS base + lane*16)
    __builtin_amdgcn_global_load_lds((gu32_t*)g, (lu32_t*)l, 16, 0, 0);
}

static __device__ inline ushort f2bf(float x) {
    union { __hip_bfloat16 h; ushort u; } cvt;
    cvt.h = __float2bfloat16(x);
    return cvt.u;
}

// One wave per row: row norms (pre-scaled by 1/ln2), attraction, bf16 casts
// (B2 pre-scaled by 2/ln2), zero rep.
__global__ __launch_bounds__(64) void prep_kernel(
    const float* __restrict__ X1, const float* __restrict__ X2,
    ushort* __restrict__ B1, ushort* __restrict__ B2,
    float* __restrict__ sq1, float* __restrict__ sq2,
    float* __restrict__ att, float* __restrict__ rep)
{
    const int i = blockIdx.x;
    const int l = threadIdx.x;            // 0..63, 2 floats each -> 128
    const float2 a = ((const float2*)(X1 + (size_t)i * D_DIM))[l];
    const float2 b = ((const float2*)(X2 + (size_t)i * D_DIM))[l];

    ushort2 pa; pa.x = f2bf(a.x);           pa.y = f2bf(a.y);
    ushort2 pb; pb.x = f2bf(b.x * SCALE_B); pb.y = f2bf(b.y * SCALE_B);
    ((ushort2*)(B1 + (size_t)i * D_DIM))[l] = pa;
    ((ushort2*)(B2 + (size_t)i * D_DIM))[l] = pb;

    float s1 = a.x * a.x + a.y * a.y;
    float s2 = b.x * b.x + b.y * b.y;
    float dx = a.x - b.x, dy = a.y - b.y;
    float ps = dx * dx + dy * dy;
    #pragma unroll
    for (int m = 32; m; m >>= 1) {
        s1 += __shfl_xor(s1, m, 64);
        s2 += __shfl_xor(s2, m, 64);
        ps += __shfl_xor(ps, m, 64);
    }
    if (l == 0) {
        sq1[i] = s1 * INV_LN2;   // log2-domain row norms
        sq2[i] = s2 * INV_LN2;
        att[i] = __expf(-ps);
        rep[i] = 0.f;
    }
}

// Fused cross-GEMM + exp2 + row-sum. 128x128 output tile per block, 4 waves.
// A tile (128x128 bf16 = 32KB) fully staged; B tile processed in two 64-col
// halves through one 16KB buffer. Half 1 is T14 reg-staged (global->reg at
// kernel start, reg->LDS after the mid barrier). LDS XOR swizzle
// byte ^= (row&15)<<4 applied on ds_read / ds_write; global_load_lds sources
// are inverse-swizzled (linear dest + inv-swz source + swz read).
__global__ __launch_bounds__(256, 3) void cross_kernel(
    const ushort* __restrict__ B1, const ushort* __restrict__ B2,
    const float* __restrict__ sq1, const float* __restrict__ sq2,
    float* __restrict__ rep)
{
    __shared__ ushort ldsA[128 * 128];   // 32 KB
    __shared__ ushort ldsB[64 * 128];    // 16 KB (one B half)
    __shared__ float  ldsRed[2][128];    // per-wx row partials

    const int t    = threadIdx.x;
    const int lane = t & 63;
    const int wid  = t >> 6;             // 0..3
    const int wy = wid >> 1, wx = wid & 1;
    const int lr = lane & 15;            // fragment row within 16
    const int kg = lane >> 4;            // k-group (0..3) == C/D row group

    const int brow = blockIdx.y * 128;
    const int bcol = blockIdx.x * 128;

    const char* gA = (const char*)(B1 + (size_t)brow * D_DIM);   // 32 KB contig
    const char* gB = (const char*)(B2 + (size_t)bcol * D_DIM);   // 32 KB contig

    // ---- T14: issue half-1 B loads to registers first (earliest) ----
    uint4 breg[4];
    #pragma unroll
    for (int it = 0; it < 4; ++it) {
        const unsigned L = 16384u + it * 4096u + wid * 1024u + lane * 16u;
        const unsigned src = L ^ (((L >> 8) & 15u) << 4);
        breg[it] = *(const uint4*)(gB + src);
    }
    // ---- stage A (32 KB) + B half 0 (16 KB) via global_load_lds ----
    #pragma unroll
    for (int it = 0; it < 8; ++it) {
        const unsigned Lb = it * 4096u + wid * 1024u;
        const unsigned L  = Lb + lane * 16u;
        const unsigned src = L ^ (((L >> 8) & 15u) << 4);
        gload_lds16(gA + src, (char*)ldsA + Lb);
    }
    #pragma unroll
    for (int it = 0; it < 4; ++it) {
        const unsigned Lb = it * 4096u + wid * 1024u;
        const unsigned L  = Lb + lane * 16u;
        const unsigned src = L ^ (((L >> 8) & 15u) << 4);
        gload_lds16(gB + src, (char*)ldsB + Lb);
    }
    __syncthreads();

    f32x4 acc[4][4];
    #pragma unroll
    for (int m = 0; m < 4; ++m)
        #pragma unroll
        for (int n = 0; n < 4; ++n)
            acc[m][n] = (f32x4){0.f, 0.f, 0.f, 0.f};

    // ---- half 0: cols wx*32 + {0,16} ----
    #pragma unroll
    for (int kc = 0; kc < 4; ++kc) {
        bf16x8 aF[4], bF[2];
        #pragma unroll
        for (int m = 0; m < 4; ++m) {
            const int row = wy * 64 + m * 16 + lr;
            const unsigned addr = (unsigned)(row * 256 + kc * 64 + kg * 16)
                                  ^ ((unsigned)(row & 15) << 4);
            aF[m] = *(const bf16x8*)((const char*)ldsA + addr);
        }
        #pragma unroll
        for (int n = 0; n < 2; ++n) {
            const int row = wx * 32 + n * 16 + lr;
            const unsigned addr = (unsigned)(row * 256 + kc * 64 + kg * 16)
                                  ^ ((unsigned)(row & 15) << 4);
            bF[n] = *(const bf16x8*)((const char*)ldsB + addr);
        }
        #pragma unroll
        for (int m = 0; m < 4; ++m)
            #pragma unroll
            for (int n = 0; n < 2; ++n)
                acc[m][n] = __builtin_amdgcn_mfma_f32_16x16x32_bf16(
                    aF[m], bF[n], acc[m][n], 0, 0, 0);
    }

    // ---- restage: write reg-held half 1 into ldsB (swizzled ds_write) ----
    __syncthreads();     // everyone done reading half 0
    #pragma unroll
    for (int it = 0; it < 4; ++it) {
        const unsigned L = it * 4096u + wid * 1024u + lane * 16u;
        const unsigned dst = L ^ (((L >> 8) & 15u) << 4);
        *(uint4*)((char*)ldsB + dst) = breg[it];
    }
    __syncthreads();

    // ---- half 1: cols 64 + wx*32 + {0,16} ----
    #pragma unroll
    for (int kc = 0; kc < 4; ++kc) {
        bf16x8 aF[4], bF[2];
        #pragma unroll
        for (int m = 0; m < 4; ++m) {
            const int row = wy * 64 + m * 16 + lr;
            const unsigned addr = (unsigned)(row * 256 + kc * 64 + kg * 16)
                                  ^ ((unsigned)(row & 15) << 4);
            aF[m] = *(const bf16x8*)((const char*)ldsA + addr);
        }
        #pragma unroll
        for (int n = 0; n < 2; ++n) {
            const int row = wx * 32 + n * 16 + lr;
            const unsigned addr = (unsigned)(row * 256 + kc * 64 + kg * 16)
                                  ^ ((unsigned)(row & 15) << 4);
            bF[n] = *(const bf16x8*)((const char*)ldsB + addr);
        }
        #pragma unroll
        for (int m = 0; m < 4; ++m)
            #pragma unroll
            for (int n = 0; n < 2; ++n)
                acc[m][2 + n] = __builtin_amdgcn_mfma_f32_16x16x32_bf16(
                    aF[m], bF[n], acc[m][2 + n], 0, 0, 0);
    }

    // ---- epilogue: t = c' - sq1' - sq2' (log2 domain), e = exp2(min(t,0)) ----
    // C/D layout (16x16x32): col = lane&15 (=lr), row = (lane>>4)*4 + reg (=kg*4+r)
    float s2c[4];
    #pragma unroll
    for (int j = 0; j < 4; ++j) {
        const int col = bcol + (j >> 1) * 64 + wx * 32 + (j & 1) * 16 + lr;
        s2c[j] = sq2[col];
    }
    #pragma unroll
    for (int m = 0; m < 4; ++m) {
        #pragma unroll
        for (int r = 0; r < 4; ++r) {
            const int rowl = wy * 64 + m * 16 + kg * 4 + r;
            const float s1v = sq1[brow + rowl];
            float partial = 0.f;
            #pragma unroll
            for (int j = 0; j < 4; ++j) {
                const float tt = acc[m][j][r] - s1v - s2c[j];
                partial += __builtin_amdgcn_exp2f(fminf(tt, 0.0f));
            }
            partial += __shfl_xor(partial, 1, 64);
            partial += __shfl_xor(partial, 2, 64);
            partial += __shfl_xor(partial, 4, 64);
            partial += __shfl_xor(partial, 8, 64);
            if (lr == 0) ldsRed[wx][rowl] = partial;   // each (wx,rowl) written once
        }
    }
    __syncthreads();
    if (t < 128) {
        atomicAdd(&rep[brow + t], ldsRed[0][t] + ldsRed[1][t]);
    }
}

// Final: loss = mean log1p((rep_i/N)/(att_i+EPS)), mean att, mean rep/N.
__global__ __launch_bounds__(256) void final_kernel(
    const float* __restrict__ rep, const float* __restrict__ att,
    float* __restrict__ out, int N)
{
    __shared__ float sm[3][4];
    const float inv = 1.0f / (float)N;
    float ls = 0.f, sa = 0.f, sr = 0.f;
    for (int i = threadIdx.x; i < N; i += 256) {
        const float rp = rep[i] * inv;
        const float at = att[i];
        ls += log1pf(rp / (at + EPS));
        sa += at;
        sr += rp;
    }
    #pragma unroll
    for (int m = 32; m; m >>= 1) {
        ls += __shfl_xor(ls, m, 64);
        sa += __shfl_xor(sa, m, 64);
        sr += __shfl_xor(sr, m, 64);
    }
    const int wid = threadIdx.x >> 6, lane = threadIdx.x & 63;
    if (lane == 0) { sm[0][wid] = ls; sm[1][wid] = sa; sm[2][wid] = sr; }
    __syncthreads();
    if (threadIdx.x == 0) {
        float L = 0.f, A = 0.f, R = 0.f;
        #pragma unroll
        for (int w = 0; w < 4; ++w) { L += sm[0][w]; A += sm[1][w]; R += sm[2][w]; }
        out[0] = L * inv;
        out[1] = A * inv;
        out[2] = R * inv;
    }
}

extern "C" void kernel_launch(void* const* d_in, const int* in_sizes, int n_in,
                              void* d_out, int out_size, void* d_ws, size_t ws_size,
                              hipStream_t stream)
{
    const float* X1 = (const float*)d_in[0];
    const float* X2 = (const float*)d_in[1];
    const int N = in_sizes[0] / D_DIM;   // 16384
    float* out = (float*)d_out;

    char* ws = (char*)d_ws;
    ushort* B1 = (ushort*)ws;                                  // N*128*2 B
    ushort* B2 = (ushort*)(ws + (size_t)N * D_DIM * 2);        // N*128*2 B
    float* sq1 = (float*)(ws + (size_t)N * D_DIM * 4);
    float* sq2 = sq1 + N;
    float* att = sq2 + N;
    float* rep = att + N;
    // total ws use: N*512 + 16*N bytes ~= 8.65 MB

    prep_kernel<<<N, 64, 0, stream>>>(X1, X2, B1, B2, sq1, sq2, att, rep);
    dim3 grid(N / 128, N / 128);
    cross_kernel<<<grid, 256, 0, stream>>>(B1, B2, sq1, sq2, rep);
    final_kernel<<<1, 256, 0, stream>>>(rep, att, out, N);
}

// Round 4
// 130.021 us; speedup vs baseline: 3.4454x; 2.0011x over previous
//
#include <hip/hip_runtime.h>
#include <hip/hip_bf16.h>

// ContrastiveLoss: N=16384, D=128.
// loss = mean_i log1p(rep_i / (att_i + EPS)), rep_i = mean_j exp(-(sq1_i+sq2_j-2*x_i.y_j))
// att_i = exp(-||x_i - y_i||^2);  TAU=0.5 => 2*TAU = 1.
// exp folded to native exp2: B2 pre-scaled by 2/ln2, sq1/sq2 by 1/ln2.
// Outputs: [loss, mean(att), mean(rep)]  (3 fp32 scalars)

#define EPS 1e-8f
#define D_DIM 128
#define INV_LN2 1.44269504088896f
#define SCALE_B 2.88539008177793f   // 2/ln2
#define NCHUNK 8                    // column chunks (XCD count)
#define NT 16                       // 128-col B-tiles per chunk (2048 cols)

typedef __attribute__((ext_vector_type(8))) short bf16x8;
typedef __attribute__((ext_vector_type(4))) float f32x4;

typedef __attribute__((address_space(1))) const unsigned int gu32_t;
typedef __attribute__((address_space(3))) unsigned int lu32_t;

static __device__ inline void gload_lds16(const void* g, void* l) {
    // 16-byte-per-lane global -> LDS direct copy (wave-uniform LDS base + lane*16)
    __builtin_amdgcn_global_load_lds((gu32_t*)g, (lu32_t*)l, 16, 0, 0);
}

static __device__ inline ushort f2bf(float x) {
    union { __hip_bfloat16 h; ushort u; } cvt;
    cvt.h = __float2bfloat16(x);
    return cvt.u;
}

// One wave per row: row norms (pre-scaled by 1/ln2), attraction, bf16 casts
// (B2 pre-scaled by 2/ln2).
__global__ __launch_bounds__(64) void prep_kernel(
    const float* __restrict__ X1, const float* __restrict__ X2,
    ushort* __restrict__ B1, ushort* __restrict__ B2,
    float* __restrict__ sq1, float* __restrict__ sq2,
    float* __restrict__ att)
{
    const int i = blockIdx.x;
    const int l = threadIdx.x;            // 0..63, 2 floats each -> 128
    const float2 a = ((const float2*)(X1 + (size_t)i * D_DIM))[l];
    const float2 b = ((const float2*)(X2 + (size_t)i * D_DIM))[l];

    ushort2 pa; pa.x = f2bf(a.x);           pa.y = f2bf(a.y);
    ushort2 pb; pb.x = f2bf(b.x * SCALE_B); pb.y = f2bf(b.y * SCALE_B);
    ((ushort2*)(B1 + (size_t)i * D_DIM))[l] = pa;
    ((ushort2*)(B2 + (size_t)i * D_DIM))[l] = pb;

    float s1 = a.x * a.x + a.y * a.y;
    float s2 = b.x * b.x + b.y * b.y;
    float dx = a.x - b.x, dy = a.y - b.y;
    float ps = dx * dx + dy * dy;
    #pragma unroll
    for (int m = 32; m; m >>= 1) {
        s1 += __shfl_xor(s1, m, 64);
        s2 += __shfl_xor(s2, m, 64);
        ps += __shfl_xor(ps, m, 64);
    }
    if (l == 0) {
        sq1[i] = s1 * INV_LN2;   // log2-domain row norms
        sq2[i] = s2 * INV_LN2;
        att[i] = __expf(-ps);
    }
}

// Fused cross-GEMM + exp2 + row-sum. Block = 128 rows x 2048 cols (16 B-tiles
// of 128 cols), 4 waves in 2x2 over each 128x128 tile. A-tile staged once and
// held in registers; B-tiles double-buffered through 2x32KB LDS with
// prefetch-early / barrier-late (2-phase pipeline). Row partials accumulate in
// registers across all tiles; ONE plain store per (row, wx) at the end into
// partials[2*NCHUNK][N] -- zero global atomics.
// LDS XOR swizzle byte ^= (row&15)<<4 on ds_read; global_load_lds sources
// inverse-swizzled (linear dest + inv-swz source + swz read).
__global__ __launch_bounds__(256, 2) void cross_kernel(
    const ushort* __restrict__ B1, const ushort* __restrict__ B2,
    const float* __restrict__ sq1, const float* __restrict__ sq2,
    float* __restrict__ partials, int Ntot)
{
    __shared__ char lds[2][32768];       // dbuf; buf0 initially holds A

    const int t    = threadIdx.x;
    const int lane = t & 63;
    const int wid  = t >> 6;             // 0..3
    const int wy = wid >> 1, wx = wid & 1;
    const int lr = lane & 15;            // fragment row within 16
    const int kg = lane >> 4;            // k-group (0..3) == C/D row group

    const int brow = blockIdx.y * 128;
    const int ccol = blockIdx.x * (NT * 128);   // chunk base column

    const char* gA = (const char*)(B1 + (size_t)brow * D_DIM);   // 32 KB contig

    // ---- stage A -> buf0 and B-tile0 -> buf1 concurrently ----
    #pragma unroll
    for (int it = 0; it < 8; ++it) {
        const unsigned Lb = it * 4096u + wid * 1024u;
        const unsigned L  = Lb + lane * 16u;
        const unsigned src = L ^ (((L >> 8) & 15u) << 4);
        gload_lds16(gA + src, lds[0] + Lb);
    }
    {
        const char* gB = (const char*)(B2 + (size_t)ccol * D_DIM);
        #pragma unroll
        for (int it = 0; it < 8; ++it) {
            const unsigned Lb = it * 4096u + wid * 1024u;
            const unsigned L  = Lb + lane * 16u;
            const unsigned src = L ^ (((L >> 8) & 15u) << 4);
            gload_lds16(gB + src, lds[1] + Lb);
        }
    }
    __syncthreads();   // vmcnt(0): A and B0 resident

    // ---- A fragments -> registers (held for whole kernel) ----
    bf16x8 aR[16];     // [m][kc] flattened m*4+kc
    #pragma unroll
    for (int m = 0; m < 4; ++m) {
        const int row = wy * 64 + m * 16 + lr;
        #pragma unroll
        for (int kc = 0; kc < 4; ++kc) {
            const unsigned addr = (unsigned)(row * 256 + kc * 64 + kg * 16)
                                  ^ ((unsigned)lr << 4);
            aR[m * 4 + kc] = *(const bf16x8*)(lds[0] + addr);
        }
    }
    // per-row constants (rows fixed per block)
    float s1c[4][4];
    #pragma unroll
    for (int m = 0; m < 4; ++m)
        #pragma unroll
        for (int r = 0; r < 4; ++r)
            s1c[m][r] = sq1[brow + wy * 64 + m * 16 + kg * 4 + r];

    __syncthreads();   // all waves done reading A: buf0 free for B-tile 1

    float p[4][4];     // row partials, accumulate across ALL tiles
    #pragma unroll
    for (int m = 0; m < 4; ++m)
        #pragma unroll
        for (int r = 0; r < 4; ++r)
            p[m][r] = 0.f;

    for (int tt = 0; tt < NT; ++tt) {
        // prefetch next B-tile into the buffer we just finished reading
        if (tt < NT - 1) {
            const char* gB = (const char*)(B2 + (size_t)(ccol + (tt + 1) * 128) * D_DIM);
            char* dst = lds[tt & 1];
            #pragma unroll
            for (int it = 0; it < 8; ++it) {
                const unsigned Lb = it * 4096u + wid * 1024u;
                const unsigned L  = Lb + lane * 16u;
                const unsigned src = L ^ (((L >> 8) & 15u) << 4);
                gload_lds16(gB + src, dst + Lb);
            }
        }
        const char* cur = lds[(tt + 1) & 1];

        f32x4 acc[4][4];
        #pragma unroll
        for (int m = 0; m < 4; ++m)
            #pragma unroll
            for (int n = 0; n < 4; ++n)
                acc[m][n] = (f32x4){0.f, 0.f, 0.f, 0.f};

        #pragma unroll
        for (int kc = 0; kc < 4; ++kc) {
            bf16x8 bF[4];
            #pragma unroll
            for (int n = 0; n < 4; ++n) {
                const int row = wx * 64 + n * 16 + lr;
                const unsigned addr = (unsigned)(row * 256 + kc * 64 + kg * 16)
                                      ^ ((unsigned)lr << 4);
                bF[n] = *(const bf16x8*)(cur + addr);
            }
            #pragma unroll
            for (int m = 0; m < 4; ++m)
                #pragma unroll
                for (int n = 0; n < 4; ++n)
                    acc[m][n] = __builtin_amdgcn_mfma_f32_16x16x32_bf16(
                        aR[m * 4 + kc], bF[n], acc[m][n], 0, 0, 0);
        }

        // epilogue: log2-domain t = c' - sq1' - sq2'; p += exp2(min(t,0))
        // C/D layout (16x16x32): col = lr, row = kg*4 + r
        float s2c[4];
        #pragma unroll
        for (int n = 0; n < 4; ++n)
            s2c[n] = sq2[ccol + tt * 128 + wx * 64 + n * 16 + lr];
        #pragma unroll
        for (int m = 0; m < 4; ++m) {
            #pragma unroll
            for (int r = 0; r < 4; ++r) {
                const float s1v = s1c[m][r];
                #pragma unroll
                for (int n = 0; n < 4; ++n) {
                    const float d = acc[m][n][r] - s1v - s2c[n];
                    p[m][r] += __builtin_amdgcn_exp2f(fminf(d, 0.0f));
                }
            }
        }
        __syncthreads();   // drains prefetch vmcnt + syncs buffer swap
    }

    // ---- reduce partials over the 16 col-lanes; one store per (row, wx) ----
    const size_t plane = (size_t)(blockIdx.x * 2 + wx) * (size_t)Ntot;
    #pragma unroll
    for (int m = 0; m < 4; ++m) {
        #pragma unroll
        for (int r = 0; r < 4; ++r) {
            float v = p[m][r];
            v += __shfl_xor(v, 1, 64);
            v += __shfl_xor(v, 2, 64);
            v += __shfl_xor(v, 4, 64);
            v += __shfl_xor(v, 8, 64);
            if (lr == 0)
                partials[plane + brow + wy * 64 + m * 16 + kg * 4 + r] = v;
        }
    }
}

// Sum the 2*NCHUNK partial planes per row.
__global__ __launch_bounds__(256) void rowsum_kernel(
    const float* __restrict__ partials, float* __restrict__ rep, int N)
{
    const int i = blockIdx.x * 256 + threadIdx.x;
    float s = 0.f;
    #pragma unroll
    for (int pl = 0; pl < 2 * NCHUNK; ++pl)
        s += partials[(size_t)pl * N + i];
    rep[i] = s;
}

// Final: loss = mean log1p((rep_i/N)/(att_i+EPS)), mean att, mean rep/N.
__global__ __launch_bounds__(256) void final_kernel(
    const float* __restrict__ rep, const float* __restrict__ att,
    float* __restrict__ out, int N)
{
    __shared__ float sm[3][4];
    const float inv = 1.0f / (float)N;
    float ls = 0.f, sa = 0.f, sr = 0.f;
    for (int i = threadIdx.x; i < N; i += 256) {
        const float rp = rep[i] * inv;
        const float at = att[i];
        ls += log1pf(rp / (at + EPS));
        sa += at;
        sr += rp;
    }
    #pragma unroll
    for (int m = 32; m; m >>= 1) {
        ls += __shfl_xor(ls, m, 64);
        sa += __shfl_xor(sa, m, 64);
        sr += __shfl_xor(sr, m, 64);
    }
    const int wid = threadIdx.x >> 6, lane = threadIdx.x & 63;
    if (lane == 0) { sm[0][wid] = ls; sm[1][wid] = sa; sm[2][wid] = sr; }
    __syncthreads();
    if (threadIdx.x == 0) {
        float L = 0.f, A = 0.f, R = 0.f;
        #pragma unroll
        for (int w = 0; w < 4; ++w) { L += sm[0][w]; A += sm[1][w]; R += sm[2][w]; }
        out[0] = L * inv;
        out[1] = A * inv;
        out[2] = R * inv;
    }
}

extern "C" void kernel_launch(void* const* d_in, const int* in_sizes, int n_in,
                              void* d_out, int out_size, void* d_ws, size_t ws_size,
                              hipStream_t stream)
{
    const float* X1 = (const float*)d_in[0];
    const float* X2 = (const float*)d_in[1];
    const int N = in_sizes[0] / D_DIM;   // 16384
    float* out = (float*)d_out;

    char* ws = (char*)d_ws;
    ushort* B1 = (ushort*)ws;                                  // N*128*2 B
    ushort* B2 = (ushort*)(ws + (size_t)N * D_DIM * 2);        // N*128*2 B
    float* sq1 = (float*)(ws + (size_t)N * D_DIM * 4);
    float* sq2 = sq1 + N;
    float* att = sq2 + N;
    float* rep = att + N;
    float* partials = rep + N;   // [2*NCHUNK][N] = 1 MB
    // total ws use: N*512 + 16*N + 2*NCHUNK*N*4 ~= 9.7 MB

    prep_kernel<<<N, 64, 0, stream>>>(X1, X2, B1, B2, sq1, sq2, att);
    dim3 grid(NCHUNK, N / 128);
    cross_kernel<<<grid, 256, 0, stream>>>(B1, B2, sq1, sq2, partials, N);
    rowsum_kernel<<<N / 256, 256, 0, stream>>>(partials, rep, N);
    final_kernel<<<1, 256, 0, stream>>>(rep, att, out, N);
}